// Round 8
// baseline (1297.214 us; speedup 1.0000x reference)
//
#include <hip/hip_runtime.h>
#include <stdint.h>

// ---------------- types ----------------
typedef __attribute__((ext_vector_type(8))) short bf16x8;   // 8 x bf16 = 4 VGPRs
typedef __attribute__((ext_vector_type(4))) short s16x4;    // 4 x bf16 = 8B
typedef __attribute__((ext_vector_type(4))) float f32x4;
typedef __attribute__((ext_vector_type(4))) unsigned u32x4;

#define AS1 __attribute__((address_space(1)))
#define AS3 __attribute__((address_space(3)))

static __device__ __forceinline__ void gload_lds16(const void* g, void* l) {
  __builtin_amdgcn_global_load_lds((const AS1 unsigned int*)g,
                                   (AS3 unsigned int*)l, 16, 0, 0);
}

// round-to-nearest-even f32 -> bf16 bits
static __device__ __forceinline__ short f2bs(float f) {
  unsigned u = __builtin_bit_cast(unsigned, f);
  unsigned r = (u + 0x7fffu + ((u >> 16) & 1u)) >> 16;
  return (short)r;
}
static __device__ __forceinline__ float bs2f(short s) {
  unsigned u = ((unsigned)(unsigned short)s) << 16;
  return __builtin_bit_cast(float, u);
}

static __device__ __forceinline__ float sigmoid_f(float x) {
  return 1.0f / (1.0f + __expf(-x));
}
static __device__ __forceinline__ float tanh_f(float x) {
  float ax = fabsf(x);
  float e  = __expf(-2.0f * ax);
  float t  = (1.0f - e) / (1.0f + e);
  return copysignf(t, x);
}

static __device__ __forceinline__ unsigned stale8(u32x4 a, u32x4 b, unsigned want) {
  return ((a[0] ^ want) | (a[1] ^ want) | (a[2] ^ want) | (a[3] ^ want) |
          (b[0] ^ want) | (b[1] ^ want) | (b[2] ^ want) | (b[3] ^ want)) & 0xffffu;
}

// constants
#define BATCH 256
#define HID   512
#define STEPS 256
#define G3    1536   // 3*HID

// ---------------- fp32 -> bf16 convert (weights) ----------------
__global__ __launch_bounds__(256) void convert_kernel(const float* __restrict__ src,
                                                      short* __restrict__ dst, int n4) {
  int i = blockIdx.x * 256 + threadIdx.x;
  if (i < n4) {
    float4 v = *(const float4*)(src + (size_t)i * 4);
    s16x4 o;
    o[0] = f2bs(v.x); o[1] = f2bs(v.y); o[2] = f2bs(v.z); o[3] = f2bs(v.w);
    *(s16x4*)(dst + (size_t)i * 4) = o;
  }
}

// ---------------- x[b][i][s] f32  ->  xT[s][b][i] bf16 ----------------
__global__ __launch_bounds__(256) void transpose_kernel(const float* __restrict__ x,
                                                        short* __restrict__ xT) {
  int bx = blockIdx.x;
  int st = bx & 7, it = (bx >> 3) & 15, b = bx >> 7;
  int s0 = st * 32, i0 = it * 32;
  int tid = threadIdx.x;
  __shared__ float tile[32][33];
  int il = tid >> 3, s4 = (tid & 7) * 4;
  float4 v = *(const float4*)(x + (size_t)b * 131072 + (size_t)(i0 + il) * 256 + s0 + s4);
  tile[il][s4 + 0] = v.x; tile[il][s4 + 1] = v.y;
  tile[il][s4 + 2] = v.z; tile[il][s4 + 3] = v.w;
  __syncthreads();
  int sl = tid >> 3, iv = (tid & 7) * 4;
  s16x4 o;
  o[0] = f2bs(tile[iv + 0][sl]); o[1] = f2bs(tile[iv + 1][sl]);
  o[2] = f2bs(tile[iv + 2][sl]); o[3] = f2bs(tile[iv + 3][sl]);
  *(xT + (size_t)(s0 + sl) * 131072 + (size_t)b * 512 + i0 + iv) = o[0],
  *(s16x4*)(xT + (size_t)(s0 + sl) * 131072 + (size_t)b * 512 + i0 + iv) = o;
}

// ---------------- phase 1: gi[m][g] = xT[m] . W_ih[g] + bias_ih[g] (bf16 out) ----
__global__ __launch_bounds__(256) void phase1_kernel(const short* __restrict__ A,
                                                     const short* __restrict__ B,
                                                     const float* __restrict__ bias,
                                                     short* __restrict__ out, int M) {
  int MT = M >> 7;
  int bx = blockIdx.x;
  int mt = bx % MT, nt = bx / MT;
  int m0 = mt * 128, n0 = nt * 128;
  int tid = threadIdx.x, w = tid >> 6, lane = tid & 63;
  int lm = lane & 15, q = lane >> 4;
  int wm = w & 1, wn = w >> 1;
  __shared__ short As[128 * 32];
  __shared__ short Bs[128 * 32];
  f32x4 acc[4][4] = {};
  int srow = lane >> 2;
  int scol = (lane & 3) * 8;

  for (int kt = 0; kt < 16; ++kt) {
#pragma unroll
    for (int i2 = 0; i2 < 2; ++i2) {
      int i = w * 2 + i2;
      int row = i * 16 + srow;
      gload_lds16(A + (size_t)(m0 + row) * 512 + kt * 32 + scol, As + i * 512);
      gload_lds16(B + (size_t)(n0 + row) * 512 + kt * 32 + scol, Bs + i * 512);
    }
    __syncthreads();
    bf16x8 av[4], bv[4];
#pragma unroll
    for (int f = 0; f < 4; ++f) {
      av[f] = *(const bf16x8*)(As + (wm * 64 + f * 16 + lm) * 32 + q * 8);
      bv[f] = *(const bf16x8*)(Bs + (wn * 64 + f * 16 + lm) * 32 + q * 8);
    }
#pragma unroll
    for (int fm = 0; fm < 4; ++fm)
#pragma unroll
      for (int fn = 0; fn < 4; ++fn)
        acc[fm][fn] = __builtin_amdgcn_mfma_f32_16x16x32_bf16(av[fm], bv[fn], acc[fm][fn], 0, 0, 0);
    __syncthreads();
  }
#pragma unroll
  for (int fn = 0; fn < 4; ++fn) {
    int g = n0 + wn * 64 + fn * 16 + lm;
    float bi = bias[g];
#pragma unroll
    for (int fm = 0; fm < 4; ++fm) {
      int rb = m0 + wm * 64 + fm * 16 + q * 4;
#pragma unroll
      for (int r = 0; r < 4; ++r)
        out[(size_t)(rb + r) * G3 + g] = f2bs(acc[fm][fn][r] + bi);
    }
  }
}

// ---------------- phase 2: persistent GRU scan ----------------
// R6 base (538us scan: R1 geometry + raw barriers) + SAFE pipelined poll:
// TWO DISJOINT, FUNCTION-SCOPE, TIED REGISTER SETS (pa*, pb*), staggered
// copies, and a check ONLY after the checked copy is RETIRED:
//   prologue: ISSUE(A); sleep; ISSUE(B)
//   loop { WAIT vmcnt(8) binding A  -> A retired (B newest 8 in flight)
//          check A -> fresh? break (A has NO loads in flight: it was not
//                     reissued after its last check) : reissue A
//          WAIT vmcnt(8) binding B  -> B retired; check B; ... }
// Why this is safe by construction (no ordering assumptions):
//  * a validated set has zero unretired loads targeting it at break — the
//    break happens INSTEAD of that set's reissue. STASH reads only stable,
//    fully-landed, tag-validated data. (R7's failure was reading registers
//    targeted by unretired same-address loads; hardware does not guarantee
//    same-address sample order.)
//  * the other set's in-flight loads land only in its own pinned registers
//    (function-scope "+v" tied everywhere -> live whole kernel -> physregs
//    pinned; excludes R5's reuse-clobber crash mode).
//  * out-of-order leftover landings (old parity) into a set are caught by
//    the per-dword tag check -> reissue washes them out. vmcnt in-order
//    retirement guarantees "retired => data written".
//  * single vmcnt(0) drain after the t-loop covers teardown.
// Check cadence ~RTT/2 (~380ns) vs R6's ~730ns -> halves detection
// quantization, the dominant per-step term.
// Tagged-dword publish protocol unchanged: dword = {bf16 h << 16 | step tag};
// dword stores single-copy atomic. Safety induction unchanged: tag t+1
// publishes only after the barrier following all waves' polls of t.
__global__ __launch_bounds__(256) void scan_kernel(const short* __restrict__ gi,
                                                   const short* __restrict__ Whh,
                                                   const float* __restrict__ bias_hh,
                                                   unsigned* __restrict__ hbuf,
                                                   float* __restrict__ hmaster,
                                                   int CH, int step_base, int first) {
  int bid = blockIdx.x;
  int xcd = bid & 7, slot = bid >> 3;
  int group = xcd + 8 * (slot >> 4);
  int j = slot & 15;
  int tid = threadIdx.x;
  int w = tid >> 6, lane = tid & 63;
  int lm = lane & 15, q = lane >> 4;
  int grow = group * 16;

  __shared__ short h_lds[16 * 520];      // padded rows: 512+8
  __shared__ float gh_lds[16][100];
  __shared__ float h_loc[512];           // [16][32] fp32 master slice
  __shared__ float bhh[96];

  // W_hh slice into registers: wave w (<3) -> gate w, 2 N-tiles of 16
  bf16x8 Bf[2][16];
  if (w < 3) {
#pragma unroll
    for (int tau = 0; tau < 2; ++tau)
#pragma unroll
      for (int kt = 0; kt < 16; ++kt) {
        int row = w * 512 + j * 32 + tau * 16 + lm;
        Bf[tau][kt] = *(const bf16x8*)(Whh + (size_t)row * 512 + kt * 32 + q * 8);
      }
  }

  if (tid < 96) {
    int p = tid >> 5, cc = tid & 31;
    bhh[tid] = bias_hh[p * 512 + j * 32 + cc];
  }
#pragma unroll
  for (int u = 0; u < 2; ++u) {
    int idx = tid + u * 256;
    int r = idx >> 5, cc = idx & 31;
    h_loc[idx] = first ? 0.0f : hmaster[(size_t)(grow + r) * 512 + j * 32 + cc];
  }
  __syncthreads();

  // per-thread gi pointers (2 elements per thread per gate), bf16
  int i0 = tid, i1 = tid + 256;
  const short* gp0 = gi + (size_t)(grow + (i0 >> 5)) * G3 + j * 32 + (i0 & 31);
  const short* gp1 = gi + (size_t)(grow + (i1 >> 5)) * G3 + j * 32 + (i1 & 31);
  const size_t gstride = (size_t)256 * G3;

  // software prefetch (plain cached loads; rides across raw barriers)
  short pg0r = gp0[0], pg0z = gp0[512], pg0n = gp0[1024];
  short pg1r = gp1[0], pg1z = gp1[512], pg1n = gp1[1024];

  // poll geometry: block reads the group's full h (16x512 tagged dwords).
  // Thread covers 8 chunks of 16B: word f = tid*4 + c*1024
  //   -> row = (tid>>7) + 2c, col = (tid&127)*4
  unsigned o0 = (unsigned)tid * 16u;          // byte offset of chunk 0
  const int r0 = tid >> 7;
  const int colb = (tid & 127) * 4;
  short* lp = h_lds + r0 * 520 + colb;        // +c*1040 shorts per chunk (2 rows)
  unsigned* grp_base = hbuf + (size_t)group * 8192;

  // pinned poll register sets (function scope, tied "+v" everywhere)
  u32x4 pa0 = {0,0,0,0}, pa1 = {0,0,0,0}, pa2 = {0,0,0,0}, pa3 = {0,0,0,0};
  u32x4 pa4 = {0,0,0,0}, pa5 = {0,0,0,0}, pa6 = {0,0,0,0}, pa7 = {0,0,0,0};
  u32x4 pb0 = {0,0,0,0}, pb1 = {0,0,0,0}, pb2 = {0,0,0,0}, pb3 = {0,0,0,0};
  u32x4 pb4 = {0,0,0,0}, pb5 = {0,0,0,0}, pb6 = {0,0,0,0}, pb7 = {0,0,0,0};

#define POLL_ISSUE(R0, R1_, R2, R3, R4, R5_, R6_, R7_)                        \
    asm volatile(                                                             \
        "global_load_dwordx4 %0, %8, %16 sc0 sc1\n\t"                         \
        "global_load_dwordx4 %1, %9, %16 sc0 sc1\n\t"                         \
        "global_load_dwordx4 %2, %10, %16 sc0 sc1\n\t"                        \
        "global_load_dwordx4 %3, %11, %16 sc0 sc1\n\t"                        \
        "global_load_dwordx4 %4, %12, %16 sc0 sc1\n\t"                        \
        "global_load_dwordx4 %5, %13, %16 sc0 sc1\n\t"                        \
        "global_load_dwordx4 %6, %14, %16 sc0 sc1\n\t"                        \
        "global_load_dwordx4 %7, %15, %16 sc0 sc1"                            \
        : "+v"(R0), "+v"(R1_), "+v"(R2), "+v"(R3),                            \
          "+v"(R4), "+v"(R5_), "+v"(R6_), "+v"(R7_)                           \
        : "v"(o0), "v"(o0 + 4096u), "v"(o0 + 8192u), "v"(o0 + 12288u),        \
          "v"(o0 + 16384u), "v"(o0 + 20480u), "v"(o0 + 24576u),               \
          "v"(o0 + 28672u), "s"(src)                                          \
        : "memory")

#define POLL_WAIT8(R0, R1_, R2, R3, R4, R5_, R6_, R7_)                        \
    asm volatile("s_waitcnt vmcnt(8)"                                         \
        : "+v"(R0), "+v"(R1_), "+v"(R2), "+v"(R3),                            \
          "+v"(R4), "+v"(R5_), "+v"(R6_), "+v"(R7_) :: "memory")

#define STALE4(R0, R1_, R2, R3)                                               \
    (stale8(R0, R1_, want) | stale8(R2, R3, want))

  for (int t = 0; t < CH; ++t) {
    int gstep = step_base + t;
    int p = gstep & 1;
    const unsigned* src = grp_base + (size_t)p * 131072;
    unsigned want = (unsigned)gstep;

    // ---- staggered dual-set poll
    POLL_ISSUE(pa0, pa1, pa2, pa3, pa4, pa5, pa6, pa7);
    __builtin_amdgcn_s_sleep(4);                 // ~107ns stagger
    POLL_ISSUE(pb0, pb1, pb2, pb3, pb4, pb5, pb6, pb7);

    int useB = 0;
    {
      int spin = 0;
      for (;;) {
        // half-round A: retire A (B = newest 8 stays in flight), check A
        POLL_WAIT8(pa0, pa1, pa2, pa3, pa4, pa5, pa6, pa7);
        __builtin_amdgcn_sched_barrier(0);
        unsigned d = STALE4(pa0, pa1, pa2, pa3) | STALE4(pa4, pa5, pa6, pa7);
        if (d == 0u || ++spin > (1 << 15)) { useB = 0; break; }
        POLL_ISSUE(pa0, pa1, pa2, pa3, pa4, pa5, pa6, pa7);
        __builtin_amdgcn_s_sleep(1);
        // half-round B: retire B, check B
        POLL_WAIT8(pb0, pb1, pb2, pb3, pb4, pb5, pb6, pb7);
        __builtin_amdgcn_sched_barrier(0);
        d = STALE4(pb0, pb1, pb2, pb3) | STALE4(pb4, pb5, pb6, pb7);
        if (d == 0u || ++spin > (1 << 15)) { useB = 1; break; }
        POLL_ISSUE(pb0, pb1, pb2, pb3, pb4, pb5, pb6, pb7);
        __builtin_amdgcn_s_sleep(1);
      }
    }

    // stash fresh h (strip tags) from the validated (retired, stable) set
#define STASH(vv, c)                                                         \
    {                                                                        \
      s16x4 o_;                                                              \
      o_[0] = (short)(vv[0] >> 16); o_[1] = (short)(vv[1] >> 16);            \
      o_[2] = (short)(vv[2] >> 16); o_[3] = (short)(vv[3] >> 16);            \
      *(s16x4*)(lp + (c) * 1040) = o_;                                       \
    }
    if (useB) {
      STASH(pb0, 0) STASH(pb1, 1) STASH(pb2, 2) STASH(pb3, 3)
      STASH(pb4, 4) STASH(pb5, 5) STASH(pb6, 6) STASH(pb7, 7)
    } else {
      STASH(pa0, 0) STASH(pa1, 1) STASH(pa2, 2) STASH(pa3, 3)
      STASH(pa4, 4) STASH(pa5, 5) STASH(pa6, 6) STASH(pa7, 7)
    }
#undef STASH

    // consume current gi prefetch; issue next step's (rides across barriers)
    float cg0r = bs2f(pg0r), cg0z = bs2f(pg0z), cg0n = bs2f(pg0n);
    float cg1r = bs2f(pg1r), cg1z = bs2f(pg1z), cg1n = bs2f(pg1n);
    {
      size_t o = (size_t)((t + 1 < CH) ? (t + 1) : t) * gstride;
      pg0r = gp0[o]; pg0z = gp0[o + 512]; pg0n = gp0[o + 1024];
      pg1r = gp1[o]; pg1z = gp1[o + 512]; pg1n = gp1[o + 1024];
    }
    // raw barrier #1: LDS ordering only (h_lds stash -> MFMA reads)
    asm volatile("s_waitcnt lgkmcnt(0)\n\ts_barrier" ::: "memory");
    __builtin_amdgcn_sched_barrier(0);

    // MFMA: gh[16 x 32] for this wave's gate; 4 independent acc chains
    if (w < 3) {
      f32x4 a0 = {0.f,0.f,0.f,0.f}, a1 = {0.f,0.f,0.f,0.f};
      f32x4 a2 = {0.f,0.f,0.f,0.f}, a3 = {0.f,0.f,0.f,0.f};
#pragma unroll
      for (int kt = 0; kt < 8; ++kt) {
        bf16x8 a = *(const bf16x8*)(h_lds + lm * 520 + kt * 32 + q * 8);
        a0 = __builtin_amdgcn_mfma_f32_16x16x32_bf16(a, Bf[0][kt], a0, 0, 0, 0);
        a1 = __builtin_amdgcn_mfma_f32_16x16x32_bf16(a, Bf[1][kt], a1, 0, 0, 0);
      }
#pragma unroll
      for (int kt = 8; kt < 16; ++kt) {
        bf16x8 a = *(const bf16x8*)(h_lds + lm * 520 + kt * 32 + q * 8);
        a2 = __builtin_amdgcn_mfma_f32_16x16x32_bf16(a, Bf[0][kt], a2, 0, 0, 0);
        a3 = __builtin_amdgcn_mfma_f32_16x16x32_bf16(a, Bf[1][kt], a3, 0, 0, 0);
      }
#pragma unroll
      for (int r = 0; r < 4; ++r) {
        gh_lds[q * 4 + r][w * 32 + lm]      = a0[r] + a2[r];
        gh_lds[q * 4 + r][w * 32 + 16 + lm] = a1[r] + a3[r];
      }
    }
    // raw barrier #2: LDS ordering only (gh_lds writes -> cell reads)
    asm volatile("s_waitcnt lgkmcnt(0)\n\ts_barrier" ::: "memory");
    __builtin_amdgcn_sched_barrier(0);

    // elementwise GRU cell + immediate tagged publish
    unsigned tagp = (unsigned)(gstep + 1);
    unsigned* dstb = grp_base + (size_t)(1 - p) * 131072;
    {
      int r = i0 >> 5, cc = i0 & 31;
      float hr = gh_lds[r][cc]      + bhh[cc];
      float hz = gh_lds[r][32 + cc] + bhh[32 + cc];
      float hn = gh_lds[r][64 + cc] + bhh[64 + cc];
      float rr = sigmoid_f(cg0r + hr);
      float zz = sigmoid_f(cg0z + hz);
      float nn = tanh_f(cg0n + rr * hn);
      float hv = (1.0f - zz) * nn + zz * h_loc[i0];
      h_loc[i0] = hv;
      unsigned val = (((unsigned)(unsigned short)f2bs(hv)) << 16) | tagp;
      unsigned* dp = dstb + r * 512 + j * 32 + cc;
      asm volatile("global_store_dword %0, %1, off sc0 sc1" :: "v"(dp), "v"(val) : "memory");
    }
    {
      int r = i1 >> 5, cc = i1 & 31;
      float hr = gh_lds[r][cc]      + bhh[cc];
      float hz = gh_lds[r][32 + cc] + bhh[32 + cc];
      float hn = gh_lds[r][64 + cc] + bhh[64 + cc];
      float rr = sigmoid_f(cg1r + hr);
      float zz = sigmoid_f(cg1z + hz);
      float nn = tanh_f(cg1n + rr * hn);
      float hv = (1.0f - zz) * nn + zz * h_loc[i1];
      h_loc[i1] = hv;
      unsigned val = (((unsigned)(unsigned short)f2bs(hv)) << 16) | tagp;
      unsigned* dp = dstb + r * 512 + j * 32 + cc;
      asm volatile("global_store_dword %0, %1, off sc0 sc1" :: "v"(dp), "v"(val) : "memory");
    }
  }
#undef POLL_ISSUE
#undef POLL_WAIT8
#undef STALE4

  // drain any leftover poll copy before teardown (once per launch)
  asm volatile("s_waitcnt vmcnt(0)" ::: "memory");

  // write fp32 state back (d_out doubles as h_master across chunk launches)
#pragma unroll
  for (int u = 0; u < 2; ++u) {
    int idx = tid + u * 256;
    int r = idx >> 5, cc = idx & 31;
    hmaster[(size_t)(grow + r) * 512 + j * 32 + cc] = h_loc[idx];
  }
}

// ---------------- host ----------------
extern "C" void kernel_launch(void* const* d_in, const int* in_sizes, int n_in,
                              void* d_out, int out_size, void* d_ws, size_t ws_size,
                              hipStream_t stream) {
  const float* x   = (const float*)d_in[0];
  const float* Wih = (const float*)d_in[1];
  const float* Whh = (const float*)d_in[2];
  const float* bih = (const float*)d_in[3];
  const float* bhh = (const float*)d_in[4];
  float* out = (float*)d_out;
  char* ws = (char*)d_ws;

  const size_t XT_BYTES   = (size_t)256 * 256 * 512 * 2;  // 64 MiB
  const size_t W_BYTES    = (size_t)1536 * 512 * 2;       // 1.5 MiB
  const size_t HBUF_BYTES = (size_t)2 * 256 * 512 * 4;    // 1 MiB (tagged dwords)
  const size_t FIXED = XT_BYTES + 2 * W_BYTES + HBUF_BYTES + 4096;

  int CH = 256;
  while (CH > 4 && FIXED + (size_t)CH * 256 * G3 * 2 > ws_size) CH >>= 1;

  size_t off = 0;
  short* gi = (short*)(ws + off);          off += (size_t)CH * 256 * G3 * 2;
  short* xT = (short*)(ws + off);          off += XT_BYTES;
  short* WihB = (short*)(ws + off);        off += W_BYTES;
  short* WhhB = (short*)(ws + off);        off += W_BYTES;
  unsigned* hbuf = (unsigned*)(ws + off);

  hipMemsetAsync(hbuf, 0, HBUF_BYTES, stream);

  convert_kernel<<<768, 256, 0, stream>>>(Wih, WihB, 196608);
  convert_kernel<<<768, 256, 0, stream>>>(Whh, WhhB, 196608);
  transpose_kernel<<<32768, 256, 0, stream>>>(x, xT);

  int nch = 256 / CH;
  for (int c = 0; c < nch; ++c) {
    int M = CH * 256;
    phase1_kernel<<<(M / 128) * 12, 256, 0, stream>>>(
        xT + (size_t)c * CH * 256 * 512, WihB, bih, gi, M);
    scan_kernel<<<256, 256, 0, stream>>>(gi, WhhB, bhh, hbuf, out,
                                         CH, c * CH, c == 0 ? 1 : 0);
  }
}

// Round 9
// 880.545 us; speedup vs baseline: 1.4732x; 1.4732x over previous
//
#include <hip/hip_runtime.h>
#include <stdint.h>

// ---------------- types ----------------
typedef __attribute__((ext_vector_type(8))) short bf16x8;   // 8 x bf16 = 4 VGPRs
typedef __attribute__((ext_vector_type(4))) short s16x4;    // 4 x bf16 = 8B
typedef __attribute__((ext_vector_type(4))) float f32x4;
typedef __attribute__((ext_vector_type(4))) unsigned u32x4;

#define AS1 __attribute__((address_space(1)))
#define AS3 __attribute__((address_space(3)))

static __device__ __forceinline__ void gload_lds16(const void* g, void* l) {
  __builtin_amdgcn_global_load_lds((const AS1 unsigned int*)g,
                                   (AS3 unsigned int*)l, 16, 0, 0);
}

// round-to-nearest-even f32 -> bf16 bits
static __device__ __forceinline__ short f2bs(float f) {
  unsigned u = __builtin_bit_cast(unsigned, f);
  unsigned r = (u + 0x7fffu + ((u >> 16) & 1u)) >> 16;
  return (short)r;
}
static __device__ __forceinline__ float bs2f(short s) {
  unsigned u = ((unsigned)(unsigned short)s) << 16;
  return __builtin_bit_cast(float, u);
}

static __device__ __forceinline__ float sigmoid_f(float x) {
  return 1.0f / (1.0f + __expf(-x));
}
static __device__ __forceinline__ float tanh_f(float x) {
  float ax = fabsf(x);
  float e  = __expf(-2.0f * ax);
  float t  = (1.0f - e) / (1.0f + e);
  return copysignf(t, x);
}

// constants
#define BATCH 256
#define HID   512
#define STEPS 256
#define G3    1536   // 3*HID

// ---------------- fp32 -> bf16 convert (weights) ----------------
__global__ __launch_bounds__(256) void convert_kernel(const float* __restrict__ src,
                                                      short* __restrict__ dst, int n4) {
  int i = blockIdx.x * 256 + threadIdx.x;
  if (i < n4) {
    float4 v = *(const float4*)(src + (size_t)i * 4);
    s16x4 o;
    o[0] = f2bs(v.x); o[1] = f2bs(v.y); o[2] = f2bs(v.z); o[3] = f2bs(v.w);
    *(s16x4*)(dst + (size_t)i * 4) = o;
  }
}

// ---------------- x[b][i][s] f32  ->  xT[s][b][i] bf16 ----------------
__global__ __launch_bounds__(256) void transpose_kernel(const float* __restrict__ x,
                                                        short* __restrict__ xT) {
  int bx = blockIdx.x;
  int st = bx & 7, it = (bx >> 3) & 15, b = bx >> 7;
  int s0 = st * 32, i0 = it * 32;
  int tid = threadIdx.x;
  __shared__ float tile[32][33];
  int il = tid >> 3, s4 = (tid & 7) * 4;
  float4 v = *(const float4*)(x + (size_t)b * 131072 + (size_t)(i0 + il) * 256 + s0 + s4);
  tile[il][s4 + 0] = v.x; tile[il][s4 + 1] = v.y;
  tile[il][s4 + 2] = v.z; tile[il][s4 + 3] = v.w;
  __syncthreads();
  int sl = tid >> 3, iv = (tid & 7) * 4;
  s16x4 o;
  o[0] = f2bs(tile[iv + 0][sl]); o[1] = f2bs(tile[iv + 1][sl]);
  o[2] = f2bs(tile[iv + 2][sl]); o[3] = f2bs(tile[iv + 3][sl]);
  *(s16x4*)(xT + (size_t)(s0 + sl) * 131072 + (size_t)b * 512 + i0 + iv) = o;
}

// ---------------- phase 1: gi[m][g] = xT[m] . W_ih[g] + bias_ih[g] (bf16 out) ----
// R9 fix: the [128][32]-short LDS tiles have 64B row stride, so the old frag
// read ds_read_b128 at (row*64 + q*16) put all 16 lanes of a phase at banks
// {0,16} -> 8-WAY BANK CONFLICT (2.94x LDS cost, m136) -> phase1 was
// LDS-read-bound (~330 TF). Fix (Guideline 4 + caveat 21): XOR-swizzle byte
// bits 4,5 with row bits 1,2. gload_lds needs a LINEAR dest, so the swizzle
// is applied as (a) pre-swizzled per-lane GLOBAL SOURCE at staging (content
// lands swizzled; 16B-block-preserving involution on the block index:
// b ^= (b>>3&1) | ((b>>4&1)<<1)), and (b) the same involution on the frag
// read address (shorts: S ^= (S>>3)&0x18). Starting banks spread to
// {0,4,...,28}, ~2 lanes/bank-slot per phase = conflict-free.
__global__ __launch_bounds__(256) void phase1_kernel(const short* __restrict__ A,
                                                     const short* __restrict__ B,
                                                     const float* __restrict__ bias,
                                                     short* __restrict__ out, int M) {
  int MT = M >> 7;
  int bx = blockIdx.x;
  int mt = bx % MT, nt = bx / MT;
  int m0 = mt * 128, n0 = nt * 128;
  int tid = threadIdx.x, w = tid >> 6, lane = tid & 63;
  int lm = lane & 15, q = lane >> 4;
  int wm = w & 1, wn = w >> 1;
  __shared__ short As[128 * 32];
  __shared__ short Bs[128 * 32];
  f32x4 acc[4][4] = {};
  // pre-swizzled source lane: flip block-bit0 with block-bit3, bit1 with bit4
  int slsw = lane ^ ((lane >> 3) & 1) ^ (((lane >> 4) & 1) << 1);
  int srow = slsw >> 2;
  int scol = (slsw & 3) * 8;

  for (int kt = 0; kt < 16; ++kt) {
#pragma unroll
    for (int i2 = 0; i2 < 2; ++i2) {
      int i = w * 2 + i2;
      int row = i * 16 + srow;
      gload_lds16(A + (size_t)(m0 + row) * 512 + kt * 32 + scol, As + i * 512);
      gload_lds16(B + (size_t)(n0 + row) * 512 + kt * 32 + scol, Bs + i * 512);
    }
    __syncthreads();
    bf16x8 av[4], bv[4];
#pragma unroll
    for (int f = 0; f < 4; ++f) {
      int Sa = (wm * 64 + f * 16 + lm) * 32 + q * 8;
      Sa ^= (Sa >> 3) & 0x18;          // read-side involution (shorts)
      int Sb = (wn * 64 + f * 16 + lm) * 32 + q * 8;
      Sb ^= (Sb >> 3) & 0x18;
      av[f] = *(const bf16x8*)(As + Sa);
      bv[f] = *(const bf16x8*)(Bs + Sb);
    }
#pragma unroll
    for (int fm = 0; fm < 4; ++fm)
#pragma unroll
      for (int fn = 0; fn < 4; ++fn)
        acc[fm][fn] = __builtin_amdgcn_mfma_f32_16x16x32_bf16(av[fm], bv[fn], acc[fm][fn], 0, 0, 0);
    __syncthreads();
  }
#pragma unroll
  for (int fn = 0; fn < 4; ++fn) {
    int g = n0 + wn * 64 + fn * 16 + lm;
    float bi = bias[g];
#pragma unroll
    for (int fm = 0; fm < 4; ++fm) {
      int rb = m0 + wm * 64 + fm * 16 + q * 4;
#pragma unroll
      for (int r = 0; r < 4; ++r)
        out[(size_t)(rb + r) * G3 + g] = f2bs(acc[fm][fn][r] + bi);
    }
  }
}

// ---------------- phase 2: persistent GRU scan ----------------
// EXACT R6 kernel (measured 538us scan; best verified). R8 proved the poll
// cadence is LLC-CONTENTION-LIMITED (~8.4MB/round across 256 blocks):
// doubling cadence doubled coherent-load demand past LLC saturation and
// REGRESSED 1.8x. This protocol (tagged-dword publish, single-bundle poll
// with s_sleep(1) pacing, raw lgkmcnt-only barriers) is the measured optimum
// of the family; scan is at its structural floor (~2.1us/step = ~1.5 detect
// + ~0.6 tail).
// Protocol: dword = {bf16 h << 16 | step tag}; dword stores single-copy
// atomic so value+tag never tear. Publishes of tag t+1 happen only after the
// barrier following all waves' polls of t -> any visible tag-t+2 word implies
// every block passed poll(t); parity double buffer covers reuse.
__global__ __launch_bounds__(256) void scan_kernel(const short* __restrict__ gi,
                                                   const short* __restrict__ Whh,
                                                   const float* __restrict__ bias_hh,
                                                   unsigned* __restrict__ hbuf,
                                                   float* __restrict__ hmaster,
                                                   int CH, int step_base, int first) {
  int bid = blockIdx.x;
  int xcd = bid & 7, slot = bid >> 3;
  int group = xcd + 8 * (slot >> 4);
  int j = slot & 15;
  int tid = threadIdx.x;
  int w = tid >> 6, lane = tid & 63;
  int lm = lane & 15, q = lane >> 4;
  int grow = group * 16;

  __shared__ short h_lds[16 * 520];      // padded rows: 512+8
  __shared__ float gh_lds[16][100];
  __shared__ float h_loc[512];           // [16][32] fp32 master slice
  __shared__ float bhh[96];

  // W_hh slice into registers: wave w (<3) -> gate w, 2 N-tiles of 16
  bf16x8 Bf[2][16];
  if (w < 3) {
#pragma unroll
    for (int tau = 0; tau < 2; ++tau)
#pragma unroll
      for (int kt = 0; kt < 16; ++kt) {
        int row = w * 512 + j * 32 + tau * 16 + lm;
        Bf[tau][kt] = *(const bf16x8*)(Whh + (size_t)row * 512 + kt * 32 + q * 8);
      }
  }

  if (tid < 96) {
    int p = tid >> 5, cc = tid & 31;
    bhh[tid] = bias_hh[p * 512 + j * 32 + cc];
  }
#pragma unroll
  for (int u = 0; u < 2; ++u) {
    int idx = tid + u * 256;
    int r = idx >> 5, cc = idx & 31;
    h_loc[idx] = first ? 0.0f : hmaster[(size_t)(grow + r) * 512 + j * 32 + cc];
  }
  __syncthreads();

  // per-thread gi pointers (2 elements per thread per gate), bf16
  int i0 = tid, i1 = tid + 256;
  const short* gp0 = gi + (size_t)(grow + (i0 >> 5)) * G3 + j * 32 + (i0 & 31);
  const short* gp1 = gi + (size_t)(grow + (i1 >> 5)) * G3 + j * 32 + (i1 & 31);
  const size_t gstride = (size_t)256 * G3;

  // software prefetch (plain cached loads; rides across raw barriers)
  short pg0r = gp0[0], pg0z = gp0[512], pg0n = gp0[1024];
  short pg1r = gp1[0], pg1z = gp1[512], pg1n = gp1[1024];

  // poll geometry: this block reads the group's full h (16 rows x 512 cols of
  // tagged dwords = 8192 words). Thread covers 8 chunks of 16B:
  //   word f = tid*4 + c*1024  ->  row = (tid>>7) + 2c, col = (tid&127)*4
  unsigned o0 = (unsigned)tid * 16u;          // byte offset of chunk 0
  const int r0 = tid >> 7;
  const int colb = (tid & 127) * 4;
  short* lp = h_lds + r0 * 520 + colb;        // +c*1040 shorts per chunk (2 rows)
  unsigned* grp_base = hbuf + (size_t)group * 8192;

  for (int t = 0; t < CH; ++t) {
    int gstep = step_base + t;
    int p = gstep & 1;
    const unsigned* src = grp_base + (size_t)p * 131072;
    unsigned want = (unsigned)gstep;

    // ---- poll: load all 8 chunks (sc0 sc1, waitcnt INSIDE the asm so the
    // tag check can never be hoisted above the wait), retry until every word
    // of this thread's share carries tag==gstep. Bounded: wrong beats hang.
    u32x4 v0, v1, v2, v3, v4, v5, v6, v7;
    int spin = 0;
    for (;;) {
      asm volatile(
          "global_load_dwordx4 %0, %8, %16 sc0 sc1\n\t"
          "global_load_dwordx4 %1, %9, %16 sc0 sc1\n\t"
          "global_load_dwordx4 %2, %10, %16 sc0 sc1\n\t"
          "global_load_dwordx4 %3, %11, %16 sc0 sc1\n\t"
          "global_load_dwordx4 %4, %12, %16 sc0 sc1\n\t"
          "global_load_dwordx4 %5, %13, %16 sc0 sc1\n\t"
          "global_load_dwordx4 %6, %14, %16 sc0 sc1\n\t"
          "global_load_dwordx4 %7, %15, %16 sc0 sc1\n\t"
          "s_waitcnt vmcnt(0)"
          : "=&v"(v0), "=&v"(v1), "=&v"(v2), "=&v"(v3),
            "=&v"(v4), "=&v"(v5), "=&v"(v6), "=&v"(v7)
          : "v"(o0), "v"(o0 + 4096u), "v"(o0 + 8192u), "v"(o0 + 12288u),
            "v"(o0 + 16384u), "v"(o0 + 20480u), "v"(o0 + 24576u), "v"(o0 + 28672u),
            "s"(src)
          : "memory");
      unsigned d;
      d  = (v0[0] ^ want) | (v0[1] ^ want) | (v0[2] ^ want) | (v0[3] ^ want);
      d |= (v1[0] ^ want) | (v1[1] ^ want) | (v1[2] ^ want) | (v1[3] ^ want);
      d |= (v2[0] ^ want) | (v2[1] ^ want) | (v2[2] ^ want) | (v2[3] ^ want);
      d |= (v3[0] ^ want) | (v3[1] ^ want) | (v3[2] ^ want) | (v3[3] ^ want);
      d |= (v4[0] ^ want) | (v4[1] ^ want) | (v4[2] ^ want) | (v4[3] ^ want);
      d |= (v5[0] ^ want) | (v5[1] ^ want) | (v5[2] ^ want) | (v5[3] ^ want);
      d |= (v6[0] ^ want) | (v6[1] ^ want) | (v6[2] ^ want) | (v6[3] ^ want);
      d |= (v7[0] ^ want) | (v7[1] ^ want) | (v7[2] ^ want) | (v7[3] ^ want);
      if (((d & 0xffffu) == 0u) || (++spin > (1 << 16))) break;
      __builtin_amdgcn_s_sleep(1);
    }

    // stash fresh h (strip tags) straight into the MFMA staging layout
#define STASH(vv, c)                                                         \
    {                                                                        \
      s16x4 o_;                                                              \
      o_[0] = (short)(vv[0] >> 16); o_[1] = (short)(vv[1] >> 16);            \
      o_[2] = (short)(vv[2] >> 16); o_[3] = (short)(vv[3] >> 16);            \
      *(s16x4*)(lp + (c) * 1040) = o_;                                       \
    }
    STASH(v0, 0) STASH(v1, 1) STASH(v2, 2) STASH(v3, 3)
    STASH(v4, 4) STASH(v5, 5) STASH(v6, 6) STASH(v7, 7)
#undef STASH

    // consume current gi prefetch; issue next step's (rides across barriers)
    float cg0r = bs2f(pg0r), cg0z = bs2f(pg0z), cg0n = bs2f(pg0n);
    float cg1r = bs2f(pg1r), cg1z = bs2f(pg1z), cg1n = bs2f(pg1n);
    {
      size_t o = (size_t)((t + 1 < CH) ? (t + 1) : t) * gstride;
      pg0r = gp0[o]; pg0z = gp0[o + 512]; pg0n = gp0[o + 1024];
      pg1r = gp1[o]; pg1z = gp1[o + 512]; pg1n = gp1[o + 1024];
    }
    // raw barrier #1: LDS ordering only (h_lds stash -> MFMA reads);
    // no vmcnt drain, so gi prefetch + publish stores ride across.
    asm volatile("s_waitcnt lgkmcnt(0)\n\ts_barrier" ::: "memory");
    __builtin_amdgcn_sched_barrier(0);

    // MFMA: gh[16 x 32] for this wave's gate; 4 independent acc chains
    if (w < 3) {
      f32x4 a0 = {0.f,0.f,0.f,0.f}, a1 = {0.f,0.f,0.f,0.f};
      f32x4 a2 = {0.f,0.f,0.f,0.f}, a3 = {0.f,0.f,0.f,0.f};
#pragma unroll
      for (int kt = 0; kt < 8; ++kt) {
        bf16x8 a = *(const bf16x8*)(h_lds + lm * 520 + kt * 32 + q * 8);
        a0 = __builtin_amdgcn_mfma_f32_16x16x32_bf16(a, Bf[0][kt], a0, 0, 0, 0);
        a1 = __builtin_amdgcn_mfma_f32_16x16x32_bf16(a, Bf[1][kt], a1, 0, 0, 0);
      }
#pragma unroll
      for (int kt = 8; kt < 16; ++kt) {
        bf16x8 a = *(const bf16x8*)(h_lds + lm * 520 + kt * 32 + q * 8);
        a2 = __builtin_amdgcn_mfma_f32_16x16x32_bf16(a, Bf[0][kt], a2, 0, 0, 0);
        a3 = __builtin_amdgcn_mfma_f32_16x16x32_bf16(a, Bf[1][kt], a3, 0, 0, 0);
      }
#pragma unroll
      for (int r = 0; r < 4; ++r) {
        gh_lds[q * 4 + r][w * 32 + lm]      = a0[r] + a2[r];
        gh_lds[q * 4 + r][w * 32 + 16 + lm] = a1[r] + a3[r];
      }
    }
    // raw barrier #2: LDS ordering only (gh_lds writes -> cell reads)
    asm volatile("s_waitcnt lgkmcnt(0)\n\ts_barrier" ::: "memory");
    __builtin_amdgcn_sched_barrier(0);

    // elementwise GRU cell + immediate tagged publish (own values only —
    // h_lds/gh_lds hazards are covered by the barriers bracketing the next
    // iteration's phases)
    unsigned tagp = (unsigned)(gstep + 1);
    unsigned* dstb = grp_base + (size_t)(1 - p) * 131072;
    {
      int r = i0 >> 5, cc = i0 & 31;
      float hr = gh_lds[r][cc]      + bhh[cc];
      float hz = gh_lds[r][32 + cc] + bhh[32 + cc];
      float hn = gh_lds[r][64 + cc] + bhh[64 + cc];
      float rr = sigmoid_f(cg0r + hr);
      float zz = sigmoid_f(cg0z + hz);
      float nn = tanh_f(cg0n + rr * hn);
      float hv = (1.0f - zz) * nn + zz * h_loc[i0];
      h_loc[i0] = hv;
      unsigned val = (((unsigned)(unsigned short)f2bs(hv)) << 16) | tagp;
      unsigned* dp = dstb + r * 512 + j * 32 + cc;
      asm volatile("global_store_dword %0, %1, off sc0 sc1" :: "v"(dp), "v"(val) : "memory");
    }
    {
      int r = i1 >> 5, cc = i1 & 31;
      float hr = gh_lds[r][cc]      + bhh[cc];
      float hz = gh_lds[r][32 + cc] + bhh[32 + cc];
      float hn = gh_lds[r][64 + cc] + bhh[64 + cc];
      float rr = sigmoid_f(cg1r + hr);
      float zz = sigmoid_f(cg1z + hz);
      float nn = tanh_f(cg1n + rr * hn);
      float hv = (1.0f - zz) * nn + zz * h_loc[i1];
      h_loc[i1] = hv;
      unsigned val = (((unsigned)(unsigned short)f2bs(hv)) << 16) | tagp;
      unsigned* dp = dstb + r * 512 + j * 32 + cc;
      asm volatile("global_store_dword %0, %1, off sc0 sc1" :: "v"(dp), "v"(val) : "memory");
    }
  }

  // write fp32 state back (d_out doubles as h_master across chunk launches)
#pragma unroll
  for (int u = 0; u < 2; ++u) {
    int idx = tid + u * 256;
    int r = idx >> 5, cc = idx & 31;
    hmaster[(size_t)(grow + r) * 512 + j * 32 + cc] = h_loc[idx];
  }
}

// ---------------- host ----------------
extern "C" void kernel_launch(void* const* d_in, const int* in_sizes, int n_in,
                              void* d_out, int out_size, void* d_ws, size_t ws_size,
                              hipStream_t stream) {
  const float* x   = (const float*)d_in[0];
  const float* Wih = (const float*)d_in[1];
  const float* Whh = (const float*)d_in[2];
  const float* bih = (const float*)d_in[3];
  const float* bhh = (const float*)d_in[4];
  float* out = (float*)d_out;
  char* ws = (char*)d_ws;

  const size_t XT_BYTES   = (size_t)256 * 256 * 512 * 2;  // 64 MiB
  const size_t W_BYTES    = (size_t)1536 * 512 * 2;       // 1.5 MiB
  const size_t HBUF_BYTES = (size_t)2 * 256 * 512 * 4;    // 1 MiB (tagged dwords)
  const size_t FIXED = XT_BYTES + 2 * W_BYTES + HBUF_BYTES + 4096;

  int CH = 256;
  while (CH > 4 && FIXED + (size_t)CH * 256 * G3 * 2 > ws_size) CH >>= 1;

  size_t off = 0;
  short* gi = (short*)(ws + off);          off += (size_t)CH * 256 * G3 * 2;
  short* xT = (short*)(ws + off);          off += XT_BYTES;
  short* WihB = (short*)(ws + off);        off += W_BYTES;
  short* WhhB = (short*)(ws + off);        off += W_BYTES;
  unsigned* hbuf = (unsigned*)(ws + off);

  hipMemsetAsync(hbuf, 0, HBUF_BYTES, stream);

  convert_kernel<<<768, 256, 0, stream>>>(Wih, WihB, 196608);
  convert_kernel<<<768, 256, 0, stream>>>(Whh, WhhB, 196608);
  transpose_kernel<<<32768, 256, 0, stream>>>(x, xT);

  int nch = 256 / CH;
  for (int c = 0; c < nch; ++c) {
    int M = CH * 256;
    phase1_kernel<<<(M / 128) * 12, 256, 0, stream>>>(
        xT + (size_t)c * CH * 256 * 512, WihB, bih, gi, M);
    scan_kernel<<<256, 256, 0, stream>>>(gi, WhhB, bhh, hbuf, out,
                                         CH, c * CH, c == 0 ? 1 : 0);
  }
}